// Round 1
// baseline (3360.294 us; speedup 1.0000x reference)
//
#include <hip/hip_runtime.h>
#include <math.h>

#define NPIX 2304      // 48*48 patch positions
#define NDIM 243       // 3*9*9 patch dim
#define PDIM 256       // filters
#define BATCH 2
#define HO 48
#define IMGH 56
#define NCH 3
#define UNFOLD 12
#define FREQ 6

// ---------------- im2col + mean subtraction ----------------
__global__ __launch_bounds__(256) void k_im2col(const float* __restrict__ I,
                                                float* __restrict__ Icol,
                                                float* __restrict__ meanp) {
    int col = blockIdx.x % NPIX;
    int b = blockIdx.x / NPIX;
    int oi = col / HO, oj = col % HO;
    int t = threadIdx.x;
    float v = 0.f;
    if (t < NDIM) {
        int c = t / 81, rem = t % 81, ki = rem / 9, kj = rem % 9;
        v = I[((size_t)(b * NCH + c) * IMGH + (oi + ki)) * IMGH + (oj + kj)];
    }
    __shared__ float red[256];
    red[t] = v;
    __syncthreads();
    for (int s = 128; s > 0; s >>= 1) {
        if (t < s) red[t] += red[t + s];
        __syncthreads();
    }
    float mean = red[0] / (float)NDIM;
    if (t < NDIM) Icol[((size_t)b * NDIM + t) * NPIX + col] = v - mean;
    if (t == 0) meanp[b * NPIX + col] = mean;
}

// ---------------- sq[b,i] = sum_c (scale[c]*X[b,c,i])^2 ----------------
__global__ void k_sq(const float* __restrict__ X, const float* __restrict__ scale,
                     float* __restrict__ sq) {
    int idx = blockIdx.x * blockDim.x + threadIdx.x;
    if (idx >= BATCH * NPIX) return;
    int b = idx / NPIX, i = idx % NPIX;
    const float* Xp = X + (size_t)b * NDIM * NPIX + i;
    float s = 0.f;
    for (int c = 0; c < NDIM; ++c) {
        float v = Xp[(size_t)c * NPIX];
        if (scale) v *= scale[c];
        s += v * v;
    }
    sq[idx] = s;
}

// ---------------- Gram: G[b,i,j] = sum_c (s_c X[c,i])(s_c X[c,j]) ----------------
__global__ __launch_bounds__(256) void k_gram(const float* __restrict__ X,
                                              const float* __restrict__ scale,
                                              float* __restrict__ G) {
    int b = blockIdx.z;
    int i0 = blockIdx.y * 64;
    int j0 = blockIdx.x * 64;
    const float* Xb = X + (size_t)b * NDIM * NPIX;
    __shared__ float As[16][64];
    __shared__ float Bs[16][64];
    int tid = threadIdx.x;
    int tx = tid % 16, ty = tid / 16;
    int lk = tid / 16;         // slab row 0..15
    int lq = (tid % 16) * 4;   // slab col quad
    float acc[4][4] = {};
    for (int k0 = 0; k0 < NDIM; k0 += 16) {
        int c = k0 + lk;
        float4 av = make_float4(0.f,0.f,0.f,0.f), bv = make_float4(0.f,0.f,0.f,0.f);
        if (c < NDIM) {
            const float* row = Xb + (size_t)c * NPIX;
            av = *reinterpret_cast<const float4*>(row + i0 + lq);
            bv = *reinterpret_cast<const float4*>(row + j0 + lq);
            if (scale) {
                float s = scale[c];
                av.x*=s; av.y*=s; av.z*=s; av.w*=s;
                bv.x*=s; bv.y*=s; bv.z*=s; bv.w*=s;
            }
        }
        __syncthreads();
        *reinterpret_cast<float4*>(&As[lk][lq]) = av;
        *reinterpret_cast<float4*>(&Bs[lk][lq]) = bv;
        __syncthreads();
        #pragma unroll
        for (int kk = 0; kk < 16; ++kk) {
            float a[4], bb[4];
            #pragma unroll
            for (int q = 0; q < 4; ++q) { a[q] = As[kk][ty*4+q]; bb[q] = Bs[kk][tx*4+q]; }
            #pragma unroll
            for (int q = 0; q < 4; ++q)
                #pragma unroll
                for (int r = 0; r < 4; ++r) acc[q][r] += a[q] * bb[r];
        }
    }
    float* Gb = G + (size_t)b * NPIX * NPIX;
    #pragma unroll
    for (int q = 0; q < 4; ++q) {
        int i = i0 + ty*4 + q;
        float4 o = make_float4(acc[q][0], acc[q][1], acc[q][2], acc[q][3]);
        *reinterpret_cast<float4*>(Gb + (size_t)i * NPIX + j0 + tx*4) = o;
    }
}

// ---------------- W@X GEMM with fused epilogues ----------------
// C[b,m,n] = epilogue( sum_k W[m,k] * X[b,k,n] )
#define EP_NONE 0
#define EP_SUBFROM 1   // C = E - WX       (E batch-indexed, M rows)
#define EP_ADD 2       // C = E + WX       (E batch-indexed, M rows)
#define EP_ADDCOL 3    // C = WX + E[b,n]  (E = mean_patch)
#define EP_SCALEROW 4  // C = WX * E[m]    (E = std0)

template<int EP>
__global__ __launch_bounds__(256) void k_wgemm(const float* __restrict__ W,
                                               const float* __restrict__ X,
                                               float* __restrict__ C,
                                               const float* __restrict__ E,
                                               int M, int K) {
    int b = blockIdx.z;
    int m0 = blockIdx.y * 64;
    int n0 = blockIdx.x * 64;
    const float* Xb = X + (size_t)b * K * NPIX;
    __shared__ float Ws[16][65];
    __shared__ float Xs[16][64];
    int tid = threadIdx.x;
    int tx = tid % 16, ty = tid / 16;
    int wm = tid / 4, wq = (tid % 4) * 4;   // W loader
    int lk = tid / 16, lq = (tid % 16) * 4; // X loader
    float acc[4][4] = {};
    int nk = (K + 15) / 16;
    for (int t = 0; t < nk; ++t) {
        int k0 = t * 16;
        float wv[4];
        int gm = m0 + wm;
        #pragma unroll
        for (int q = 0; q < 4; ++q) {
            int k = k0 + wq + q;
            wv[q] = (gm < M && k < K) ? W[(size_t)gm * K + k] : 0.f;
        }
        float4 xv = make_float4(0.f,0.f,0.f,0.f);
        int gk = k0 + lk;
        if (gk < K) xv = *reinterpret_cast<const float4*>(Xb + (size_t)gk * NPIX + n0 + lq);
        __syncthreads();
        #pragma unroll
        for (int q = 0; q < 4; ++q) Ws[wq + q][wm] = wv[q];
        *reinterpret_cast<float4*>(&Xs[lk][lq]) = xv;
        __syncthreads();
        #pragma unroll
        for (int kk = 0; kk < 16; ++kk) {
            float a[4], bb[4];
            #pragma unroll
            for (int q = 0; q < 4; ++q) { a[q] = Ws[kk][ty*4+q]; bb[q] = Xs[kk][tx*4+q]; }
            #pragma unroll
            for (int q = 0; q < 4; ++q)
                #pragma unroll
                for (int r = 0; r < 4; ++r) acc[q][r] += a[q] * bb[r];
        }
    }
    float* Cb = C + (size_t)b * M * NPIX;
    const float* Eb = (EP == EP_SUBFROM || EP == EP_ADD) ? E + (size_t)b * M * NPIX : E;
    #pragma unroll
    for (int q = 0; q < 4; ++q) {
        int m = m0 + ty*4 + q;
        if (m >= M) break;
        size_t off = (size_t)m * NPIX + n0 + tx*4;
        float o[4];
        #pragma unroll
        for (int r = 0; r < 4; ++r) {
            float v = acc[q][r];
            if (EP == EP_SUBFROM)       v = Eb[off + r] - v;
            else if (EP == EP_ADD)      v = Eb[off + r] + v;
            else if (EP == EP_ADDCOL)   v = v + E[b * NPIX + n0 + tx*4 + r];
            else if (EP == EP_SCALEROW) v = v * E[m];
            o[r] = v;
        }
        *reinterpret_cast<float4*>(Cb + off) = make_float4(o[0], o[1], o[2], o[3]);
    }
}

// ---------------- row softmax (transposed store) with optional blend ----------------
// S[b,j,i] = softmax_i( 2*G[b,j,i] - sq[b,i] )   (== sim[i,j], via symmetry of G)
template<int BLEND>
__global__ __launch_bounds__(256) void k_softmax(float* __restrict__ G,
                                                 const float* __restrict__ sq,
                                                 float* __restrict__ S,
                                                 const float* __restrict__ nu) {
    int b = blockIdx.x / NPIX;
    int j = blockIdx.x % NPIX;
    float* Grow = G + ((size_t)b * NPIX + j) * NPIX;
    const float* sqb = sq + b * NPIX;
    int t = threadIdx.x;
    __shared__ float red[256];
    float m = -1e30f;
    for (int i = t; i < NPIX; i += 256) {
        float v = 2.f * Grow[i] - sqb[i];
        m = fmaxf(m, v);
    }
    red[t] = m; __syncthreads();
    for (int s = 128; s > 0; s >>= 1) { if (t < s) red[t] = fmaxf(red[t], red[t+s]); __syncthreads(); }
    m = red[0];
    __syncthreads();
    float ssum = 0.f;
    for (int i = t; i < NPIX; i += 256) {
        float e = expf(2.f * Grow[i] - sqb[i] - m);
        Grow[i] = e;
        ssum += e;
    }
    red[t] = ssum; __syncthreads();
    for (int s = 128; s > 0; s >>= 1) { if (t < s) red[t] += red[t+s]; __syncthreads(); }
    float inv = 1.f / red[0];
    float* Srow = S + ((size_t)b * NPIX + j) * NPIX;
    if (BLEND) {
        float nus = 1.f / (1.f + expf(-nu[0]));
        for (int i = t; i < NPIX; i += 256)
            Srow[i] = (1.f - nus) * Srow[i] + nus * (Grow[i] * inv);
    } else {
        for (int i = t; i < NPIX; i += 256)
            Srow[i] = Grow[i] * inv;
    }
}

// ---------------- group prox: out = relu(1 - theta/norm2) * A ----------------
// norm2[p,j] = sqrt( sum_i A[p,i]^2 * S[j,i] + 1e-8 ), support == 1
__global__ __launch_bounds__(256) void k_prox(const float* __restrict__ A,
                                              const float* __restrict__ S,
                                              const float* __restrict__ theta,
                                              float* __restrict__ Out) {
    int b = blockIdx.z;
    int p0 = blockIdx.y * 64;
    int j0 = blockIdx.x * 64;
    const float* Ab = A + (size_t)b * PDIM * NPIX;
    const float* Sb = S + (size_t)b * NPIX * NPIX;
    __shared__ float As[16][65];
    __shared__ float Bs[16][65];
    int tid = threadIdx.x;
    int tx = tid % 16, ty = tid / 16;
    int lm = tid / 4, lq = (tid % 4) * 4;
    float acc[4][4] = {};
    for (int k0 = 0; k0 < NPIX; k0 += 16) {
        float4 av = *reinterpret_cast<const float4*>(Ab + (size_t)(p0 + lm) * NPIX + k0 + lq);
        float4 bv = *reinterpret_cast<const float4*>(Sb + (size_t)(j0 + lm) * NPIX + k0 + lq);
        __syncthreads();
        As[lq+0][lm] = av.x*av.x; As[lq+1][lm] = av.y*av.y;
        As[lq+2][lm] = av.z*av.z; As[lq+3][lm] = av.w*av.w;
        Bs[lq+0][lm] = bv.x; Bs[lq+1][lm] = bv.y;
        Bs[lq+2][lm] = bv.z; Bs[lq+3][lm] = bv.w;
        __syncthreads();
        #pragma unroll
        for (int kk = 0; kk < 16; ++kk) {
            float a[4], bb[4];
            #pragma unroll
            for (int q = 0; q < 4; ++q) { a[q] = As[kk][ty*4+q]; bb[q] = Bs[kk][tx*4+q]; }
            #pragma unroll
            for (int q = 0; q < 4; ++q)
                #pragma unroll
                for (int r = 0; r < 4; ++r) acc[q][r] += a[q] * bb[r];
        }
    }
    float* Ob = Out + (size_t)b * PDIM * NPIX;
    #pragma unroll
    for (int q = 0; q < 4; ++q) {
        int p = p0 + ty*4 + q;
        float th = theta[p];
        size_t off = (size_t)p * NPIX + j0 + tx*4;
        float4 g = *reinterpret_cast<const float4*>(Ab + off);
        float o[4];
        float n0v = sqrtf(acc[q][0] + 1e-8f);
        float n1v = sqrtf(acc[q][1] + 1e-8f);
        float n2v = sqrtf(acc[q][2] + 1e-8f);
        float n3v = sqrtf(acc[q][3] + 1e-8f);
        o[0] = fmaxf(1.f - th / n0v, 0.f) * g.x;
        o[1] = fmaxf(1.f - th / n1v, 0.f) * g.y;
        o[2] = fmaxf(1.f - th / n2v, 0.f) * g.z;
        o[3] = fmaxf(1.f - th / n3v, 0.f) * g.w;
        *reinterpret_cast<float4*>(Ob + off) = make_float4(o[0], o[1], o[2], o[3]);
    }
}

// ---------------- col2im with overlap averaging ----------------
__global__ void k_col2im(const float* __restrict__ T, float* __restrict__ out) {
    int idx = blockIdx.x * blockDim.x + threadIdx.x;
    int total = BATCH * NCH * IMGH * IMGH;
    if (idx >= total) return;
    int x = idx % IMGH; int tmp = idx / IMGH;
    int y = tmp % IMGH; tmp /= IMGH;
    int c = tmp % NCH; int b = tmp / NCH;
    int kiLo = max(0, y - (HO - 1)), kiHi = min(8, y);
    int kjLo = max(0, x - (HO - 1)), kjHi = min(8, x);
    float s = 0.f;
    for (int ki = kiLo; ki <= kiHi; ++ki)
        for (int kj = kjLo; kj <= kjHi; ++kj) {
            int ch = c * 81 + ki * 9 + kj;
            s += T[((size_t)b * NDIM + ch) * NPIX + (y - ki) * HO + (x - kj)];
        }
    int cnt = (kiHi - kiLo + 1) * (kjHi - kjLo + 1);
    out[idx] = s / (float)cnt;
}

extern "C" void kernel_launch(void* const* d_in, const int* in_sizes, int n_in,
                              void* d_out, int out_size, void* d_ws, size_t ws_size,
                              hipStream_t stream) {
    const float* I    = (const float*)d_in[0];
    const float* Wa   = (const float*)d_in[1];  // (256,243)
    const float* Wd   = (const float*)d_in[2];  // (243,256)
    const float* Ww   = (const float*)d_in[3];  // (243,256)
    const float* std0 = (const float*)d_in[4];  // (243)
    const float* lmb  = (const float*)d_in[5];  // (12,256)
    const float* nu   = (const float*)d_in[6];  // (1)
    float* out = (float*)d_out;
    float* ws = (float*)d_ws;

    size_t off = 0;
    auto alloc = [&](size_t n) { float* p = ws + off; off += (n + 63) & ~(size_t)63; return p; };
    float* Icol  = alloc((size_t)BATCH * NDIM * NPIX);
    float* TR    = alloc((size_t)BATCH * NDIM * NPIX);   // residual / refresh proj / out_all
    float* gamma = alloc((size_t)BATCH * PDIM * NPIX);
    float* Abuf  = alloc((size_t)BATCH * PDIM * NPIX);
    float* G     = alloc((size_t)BATCH * NPIX * NPIX);
    float* S     = alloc((size_t)BATCH * NPIX * NPIX);
    float* meanp = alloc((size_t)BATCH * NPIX);
    float* sqb   = alloc((size_t)BATCH * NPIX);
    (void)ws_size; (void)in_sizes; (void)n_in; (void)out_size;

    dim3 blk(256);
    // im2col + mean subtract
    k_im2col<<<dim3(BATCH * NPIX), blk, 0, stream>>>(I, Icol, meanp);
    // initial similarity
    k_sq<<<dim3((BATCH * NPIX + 255) / 256), blk, 0, stream>>>(Icol, std0, sqb);
    k_gram<<<dim3(NPIX / 64, NPIX / 64, BATCH), blk, 0, stream>>>(Icol, std0, G);
    k_softmax<0><<<dim3(BATCH * NPIX), blk, 0, stream>>>(G, sqb, S, nu);
    // gamma = prox(Wa @ Icol)
    k_wgemm<EP_NONE><<<dim3(NPIX / 64, (PDIM + 63) / 64, BATCH), blk, 0, stream>>>(
        Wa, Icol, Abuf, nullptr, PDIM, NDIM);
    k_prox<<<dim3(NPIX / 64, PDIM / 64, BATCH), blk, 0, stream>>>(Abuf, S, lmb, gamma);

    for (int k = 0; k < UNFOLD - 1; ++k) {
        if (k % FREQ == 0 && k != 0) {
            // sim refresh: T = std0 * (Ww @ gamma); sim = (1-nus)*sim + nus*softmax(T)
            k_wgemm<EP_SCALEROW><<<dim3(NPIX / 64, (NDIM + 63) / 64, BATCH), blk, 0, stream>>>(
                Ww, gamma, TR, std0, NDIM, PDIM);
            k_sq<<<dim3((BATCH * NPIX + 255) / 256), blk, 0, stream>>>(TR, nullptr, sqb);
            k_gram<<<dim3(NPIX / 64, NPIX / 64, BATCH), blk, 0, stream>>>(TR, nullptr, G);
            k_softmax<1><<<dim3(BATCH * NPIX), blk, 0, stream>>>(G, sqb, S, nu);
        }
        // R = Icol - Wd @ gamma
        k_wgemm<EP_SUBFROM><<<dim3(NPIX / 64, (NDIM + 63) / 64, BATCH), blk, 0, stream>>>(
            Wd, gamma, TR, Icol, NDIM, PDIM);
        // A = gamma + Wa @ R
        k_wgemm<EP_ADD><<<dim3(NPIX / 64, (PDIM + 63) / 64, BATCH), blk, 0, stream>>>(
            Wa, TR, Abuf, gamma, PDIM, NDIM);
        // gamma = prox(A)
        k_prox<<<dim3(NPIX / 64, PDIM / 64, BATCH), blk, 0, stream>>>(
            Abuf, S, lmb + (size_t)(k + 1) * PDIM, gamma);
    }
    // out_all = Ww @ gamma + mean
    k_wgemm<EP_ADDCOL><<<dim3(NPIX / 64, (NDIM + 63) / 64, BATCH), blk, 0, stream>>>(
        Ww, gamma, TR, meanp, NDIM, PDIM);
    // fold back with overlap averaging
    k_col2im<<<dim3((BATCH * NCH * IMGH * IMGH + 255) / 256), blk, 0, stream>>>(TR, out);
}

// Round 2
// 1512.267 us; speedup vs baseline: 2.2220x; 2.2220x over previous
//
#include <hip/hip_runtime.h>
#include <math.h>

#define NPIX 2304      // 48*48 patch positions
#define NDIM 243       // 3*9*9 patch dim
#define PDIM 256       // filters
#define BATCH 2
#define HO 48
#define IMGH 56
#define NCH 3
#define UNFOLD 12
#define FREQ 6

typedef __attribute__((ext_vector_type(8))) short bf16x8;
typedef __attribute__((ext_vector_type(4))) float f32x4;

__device__ inline unsigned short f2bf(float x) {
    union { float f; unsigned u; } v; v.f = x;
    unsigned r = (v.u + 0x7FFFu + ((v.u >> 16) & 1u)) >> 16;
    return (unsigned short)r;
}
__device__ inline float bf2f(unsigned short u) {
    return __uint_as_float(((unsigned)u) << 16);
}

// ---------------- im2col + mean subtraction ----------------
__global__ __launch_bounds__(256) void k_im2col(const float* __restrict__ I,
                                                float* __restrict__ Icol,
                                                float* __restrict__ meanp) {
    int col = blockIdx.x % NPIX;
    int b = blockIdx.x / NPIX;
    int oi = col / HO, oj = col % HO;
    int t = threadIdx.x;
    float v = 0.f;
    if (t < NDIM) {
        int c = t / 81, rem = t % 81, ki = rem / 9, kj = rem % 9;
        v = I[((size_t)(b * NCH + c) * IMGH + (oi + ki)) * IMGH + (oj + kj)];
    }
    __shared__ float red[256];
    red[t] = v;
    __syncthreads();
    for (int s = 128; s > 0; s >>= 1) {
        if (t < s) red[t] += red[t + s];
        __syncthreads();
    }
    float mean = red[0] / (float)NDIM;
    if (t < NDIM) Icol[((size_t)b * NDIM + t) * NPIX + col] = v - mean;
    if (t == 0) meanp[b * NPIX + col] = mean;
}

// ---------------- sq[b,i] = sum_c (scale[c]*X[b,c,i])^2 ----------------
__global__ void k_sq(const float* __restrict__ X, const float* __restrict__ scale,
                     float* __restrict__ sq) {
    int idx = blockIdx.x * blockDim.x + threadIdx.x;
    if (idx >= BATCH * NPIX) return;
    int b = idx / NPIX, i = idx % NPIX;
    const float* Xp = X + (size_t)b * NDIM * NPIX + i;
    float s = 0.f;
    for (int c = 0; c < NDIM; ++c) {
        float v = Xp[(size_t)c * NPIX];
        if (scale) v *= scale[c];
        s += v * v;
    }
    sq[idx] = s;
}

// ---------------- Gram: G[b,i,j] = sum_c (s_c X[c,i])(s_c X[c,j]) ----------------
__global__ __launch_bounds__(256) void k_gram(const float* __restrict__ X,
                                              const float* __restrict__ scale,
                                              float* __restrict__ G) {
    int b = blockIdx.z;
    int i0 = blockIdx.y * 64;
    int j0 = blockIdx.x * 64;
    const float* Xb = X + (size_t)b * NDIM * NPIX;
    __shared__ float As[16][64];
    __shared__ float Bs[16][64];
    int tid = threadIdx.x;
    int tx = tid % 16, ty = tid / 16;
    int lk = tid / 16;         // slab row 0..15
    int lq = (tid % 16) * 4;   // slab col quad
    float acc[4][4] = {};
    for (int k0 = 0; k0 < NDIM; k0 += 16) {
        int c = k0 + lk;
        float4 av = make_float4(0.f,0.f,0.f,0.f), bv = make_float4(0.f,0.f,0.f,0.f);
        if (c < NDIM) {
            const float* row = Xb + (size_t)c * NPIX;
            av = *reinterpret_cast<const float4*>(row + i0 + lq);
            bv = *reinterpret_cast<const float4*>(row + j0 + lq);
            if (scale) {
                float s = scale[c];
                av.x*=s; av.y*=s; av.z*=s; av.w*=s;
                bv.x*=s; bv.y*=s; bv.z*=s; bv.w*=s;
            }
        }
        __syncthreads();
        *reinterpret_cast<float4*>(&As[lk][lq]) = av;
        *reinterpret_cast<float4*>(&Bs[lk][lq]) = bv;
        __syncthreads();
        #pragma unroll
        for (int kk = 0; kk < 16; ++kk) {
            float a[4], bb[4];
            #pragma unroll
            for (int q = 0; q < 4; ++q) { a[q] = As[kk][ty*4+q]; bb[q] = Bs[kk][tx*4+q]; }
            #pragma unroll
            for (int q = 0; q < 4; ++q)
                #pragma unroll
                for (int r = 0; r < 4; ++r) acc[q][r] += a[q] * bb[r];
        }
    }
    float* Gb = G + (size_t)b * NPIX * NPIX;
    #pragma unroll
    for (int q = 0; q < 4; ++q) {
        int i = i0 + ty*4 + q;
        float4 o = make_float4(acc[q][0], acc[q][1], acc[q][2], acc[q][3]);
        *reinterpret_cast<float4*>(Gb + (size_t)i * NPIX + j0 + tx*4) = o;
    }
}

// ---------------- W@X GEMM with fused epilogues ----------------
// C[b,m,n] = epilogue( sum_k W[m,k] * X[b,k,n] ); optional bf16(C^2) side-write
#define EP_NONE 0
#define EP_SUBFROM 1   // C = E - WX       (E batch-indexed, M rows)
#define EP_ADD 2       // C = E + WX       (E batch-indexed, M rows)
#define EP_ADDCOL 3    // C = WX + E[b,n]  (E = mean_patch)
#define EP_SCALEROW 4  // C = WX * E[m]    (E = std0)

template<int EP, int WSQ>
__global__ __launch_bounds__(256) void k_wgemm(const float* __restrict__ W,
                                               const float* __restrict__ X,
                                               float* __restrict__ C,
                                               const float* __restrict__ E,
                                               unsigned short* __restrict__ Csq,
                                               int M, int K) {
    int b = blockIdx.z;
    int m0 = blockIdx.y * 64;
    int n0 = blockIdx.x * 64;
    const float* Xb = X + (size_t)b * K * NPIX;
    __shared__ float Ws[16][65];
    __shared__ float Xs[16][64];
    int tid = threadIdx.x;
    int tx = tid % 16, ty = tid / 16;
    int wm = tid / 4, wq = (tid % 4) * 4;   // W loader
    int lk = tid / 16, lq = (tid % 16) * 4; // X loader
    float acc[4][4] = {};
    int nk = (K + 15) / 16;
    for (int t = 0; t < nk; ++t) {
        int k0 = t * 16;
        float wv[4];
        int gm = m0 + wm;
        #pragma unroll
        for (int q = 0; q < 4; ++q) {
            int k = k0 + wq + q;
            wv[q] = (gm < M && k < K) ? W[(size_t)gm * K + k] : 0.f;
        }
        float4 xv = make_float4(0.f,0.f,0.f,0.f);
        int gk = k0 + lk;
        if (gk < K) xv = *reinterpret_cast<const float4*>(Xb + (size_t)gk * NPIX + n0 + lq);
        __syncthreads();
        #pragma unroll
        for (int q = 0; q < 4; ++q) Ws[wq + q][wm] = wv[q];
        *reinterpret_cast<float4*>(&Xs[lk][lq]) = xv;
        __syncthreads();
        #pragma unroll
        for (int kk = 0; kk < 16; ++kk) {
            float a[4], bb[4];
            #pragma unroll
            for (int q = 0; q < 4; ++q) { a[q] = Ws[kk][ty*4+q]; bb[q] = Xs[kk][tx*4+q]; }
            #pragma unroll
            for (int q = 0; q < 4; ++q)
                #pragma unroll
                for (int r = 0; r < 4; ++r) acc[q][r] += a[q] * bb[r];
        }
    }
    float* Cb = C + (size_t)b * M * NPIX;
    const float* Eb = (EP == EP_SUBFROM || EP == EP_ADD) ? E + (size_t)b * M * NPIX : E;
    #pragma unroll
    for (int q = 0; q < 4; ++q) {
        int m = m0 + ty*4 + q;
        if (m >= M) break;
        size_t off = (size_t)m * NPIX + n0 + tx*4;
        float o[4];
        #pragma unroll
        for (int r = 0; r < 4; ++r) {
            float v = acc[q][r];
            if (EP == EP_SUBFROM)       v = Eb[off + r] - v;
            else if (EP == EP_ADD)      v = Eb[off + r] + v;
            else if (EP == EP_ADDCOL)   v = v + E[b * NPIX + n0 + tx*4 + r];
            else if (EP == EP_SCALEROW) v = v * E[m];
            o[r] = v;
        }
        *reinterpret_cast<float4*>(Cb + off) = make_float4(o[0], o[1], o[2], o[3]);
        if (WSQ) {
            unsigned short* Qb = Csq + (size_t)b * M * NPIX + off;
            #pragma unroll
            for (int r = 0; r < 4; ++r) Qb[r] = f2bf(o[r] * o[r]);
        }
    }
}

// ---------------- row softmax -> bf16 transposed sim, optional blend ----------------
// Sbf[b,j,i] = softmax_i( 2*G[b,j,i] - sq[b,i] )   (== sim[i,j], via symmetry of G)
template<int BLEND>
__global__ __launch_bounds__(256) void k_softmax(float* __restrict__ G,
                                                 const float* __restrict__ sq,
                                                 unsigned short* __restrict__ Sbf,
                                                 const float* __restrict__ nu) {
    int b = blockIdx.x / NPIX;
    int j = blockIdx.x % NPIX;
    float* Grow = G + ((size_t)b * NPIX + j) * NPIX;
    const float* sqb = sq + b * NPIX;
    int t = threadIdx.x;
    __shared__ float red[256];
    float m = -1e30f;
    for (int i = t; i < NPIX; i += 256) {
        float v = 2.f * Grow[i] - sqb[i];
        m = fmaxf(m, v);
    }
    red[t] = m; __syncthreads();
    for (int s = 128; s > 0; s >>= 1) { if (t < s) red[t] = fmaxf(red[t], red[t+s]); __syncthreads(); }
    m = red[0];
    __syncthreads();
    float ssum = 0.f;
    for (int i = t; i < NPIX; i += 256) {
        float e = expf(2.f * Grow[i] - sqb[i] - m);
        Grow[i] = e;
        ssum += e;
    }
    red[t] = ssum; __syncthreads();
    for (int s = 128; s > 0; s >>= 1) { if (t < s) red[t] += red[t+s]; __syncthreads(); }
    float inv = 1.f / red[0];
    unsigned short* Srow = Sbf + ((size_t)b * NPIX + j) * NPIX;
    if (BLEND) {
        float nus = 1.f / (1.f + expf(-nu[0]));
        for (int i = t; i < NPIX; i += 256)
            Srow[i] = f2bf((1.f - nus) * bf2f(Srow[i]) + nus * (Grow[i] * inv));
    } else {
        for (int i = t; i < NPIX; i += 256)
            Srow[i] = f2bf(Grow[i] * inv);
    }
}

// ---------------- MFMA group prox ----------------
// norm2sq[p,j] = sum_i A2[p,i] * S[j,i]  (bf16 x bf16 -> fp32, split-K by 4 waves)
// Out[p,j] = relu(1 - theta[p]/sqrt(norm2sq+1e-8)) * A[p,j]
__global__ __launch_bounds__(256) void k_prox_mfma(const unsigned short* __restrict__ A2,
                                                   const unsigned short* __restrict__ Sbf,
                                                   const float* __restrict__ A,
                                                   const float* __restrict__ theta,
                                                   float* __restrict__ Out) {
    int b = blockIdx.z;
    int p0 = blockIdx.y * 16;
    int j0 = blockIdx.x * 64;
    int tid = threadIdx.x;
    int w = tid >> 6;        // wave id -> K chunk
    int l = tid & 63;
    int lm = l & 15;
    int kh = l >> 4;         // 0..3
    const unsigned short* Ap = A2 + ((size_t)b * PDIM + p0 + lm) * NPIX + kh * 8;
    const unsigned short* Sp = Sbf + ((size_t)b * NPIX + j0 + lm) * NPIX + kh * 8;
    f32x4 acc[4];
    #pragma unroll
    for (int n = 0; n < 4; ++n) acc[n] = (f32x4){0.f, 0.f, 0.f, 0.f};
    int kbeg = w * (NPIX / 4);
    int kend = kbeg + NPIX / 4;
    for (int k = kbeg; k < kend; k += 32) {
        bf16x8 a = *reinterpret_cast<const bf16x8*>(Ap + k);
        #pragma unroll
        for (int n = 0; n < 4; ++n) {
            bf16x8 bf = *reinterpret_cast<const bf16x8*>(Sp + (size_t)n * 16 * NPIX + k);
            acc[n] = __builtin_amdgcn_mfma_f32_16x16x32_bf16(a, bf, acc[n], 0, 0, 0);
        }
    }
    __shared__ float red[4][16][65];
    #pragma unroll
    for (int n = 0; n < 4; ++n)
        #pragma unroll
        for (int r = 0; r < 4; ++r)
            red[w][kh * 4 + r][n * 16 + lm] = acc[n][r];
    __syncthreads();
    #pragma unroll
    for (int r = 0; r < 4; ++r) {
        int linear = tid + r * 256;
        int m = linear >> 6, n = linear & 63;
        float s = red[0][m][n] + red[1][m][n] + red[2][m][n] + red[3][m][n];
        float n2 = sqrtf(s + 1e-8f);
        float th = theta[p0 + m];
        size_t off = ((size_t)b * PDIM + p0 + m) * NPIX + j0 + n;
        Out[off] = fmaxf(1.f - th / n2, 0.f) * A[off];
    }
}

// ---------------- col2im with overlap averaging ----------------
__global__ void k_col2im(const float* __restrict__ T, float* __restrict__ out) {
    int idx = blockIdx.x * blockDim.x + threadIdx.x;
    int total = BATCH * NCH * IMGH * IMGH;
    if (idx >= total) return;
    int x = idx % IMGH; int tmp = idx / IMGH;
    int y = tmp % IMGH; tmp /= IMGH;
    int c = tmp % NCH; int b = tmp / NCH;
    int kiLo = max(0, y - (HO - 1)), kiHi = min(8, y);
    int kjLo = max(0, x - (HO - 1)), kjHi = min(8, x);
    float s = 0.f;
    for (int ki = kiLo; ki <= kiHi; ++ki)
        for (int kj = kjLo; kj <= kjHi; ++kj) {
            int ch = c * 81 + ki * 9 + kj;
            s += T[((size_t)b * NDIM + ch) * NPIX + (y - ki) * HO + (x - kj)];
        }
    int cnt = (kiHi - kiLo + 1) * (kjHi - kjLo + 1);
    out[idx] = s / (float)cnt;
}

extern "C" void kernel_launch(void* const* d_in, const int* in_sizes, int n_in,
                              void* d_out, int out_size, void* d_ws, size_t ws_size,
                              hipStream_t stream) {
    const float* I    = (const float*)d_in[0];
    const float* Wa   = (const float*)d_in[1];  // (256,243)
    const float* Wd   = (const float*)d_in[2];  // (243,256)
    const float* Ww   = (const float*)d_in[3];  // (243,256)
    const float* std0 = (const float*)d_in[4];  // (243)
    const float* lmb  = (const float*)d_in[5];  // (12,256)
    const float* nu   = (const float*)d_in[6];  // (1)
    float* out = (float*)d_out;
    float* ws = (float*)d_ws;

    size_t off = 0;
    auto alloc = [&](size_t n) { float* p = ws + off; off += (n + 63) & ~(size_t)63; return p; };
    float* Icol  = alloc((size_t)BATCH * NDIM * NPIX);
    float* TR    = alloc((size_t)BATCH * NDIM * NPIX);   // residual / refresh proj / out_all
    float* gamma = alloc((size_t)BATCH * PDIM * NPIX);
    float* Abuf  = alloc((size_t)BATCH * PDIM * NPIX);
    float* G     = alloc((size_t)BATCH * NPIX * NPIX);
    unsigned short* Sbf = (unsigned short*)alloc((size_t)BATCH * NPIX * NPIX / 2);
    unsigned short* A2  = (unsigned short*)alloc((size_t)BATCH * PDIM * NPIX / 2);
    float* meanp = alloc((size_t)BATCH * NPIX);
    float* sqb   = alloc((size_t)BATCH * NPIX);
    (void)ws_size; (void)in_sizes; (void)n_in; (void)out_size;

    dim3 blk(256);
    dim3 gProx(NPIX / 64, PDIM / 16, BATCH);
    // im2col + mean subtract
    k_im2col<<<dim3(BATCH * NPIX), blk, 0, stream>>>(I, Icol, meanp);
    // initial similarity
    k_sq<<<dim3((BATCH * NPIX + 255) / 256), blk, 0, stream>>>(Icol, std0, sqb);
    k_gram<<<dim3(NPIX / 64, NPIX / 64, BATCH), blk, 0, stream>>>(Icol, std0, G);
    k_softmax<0><<<dim3(BATCH * NPIX), blk, 0, stream>>>(G, sqb, Sbf, nu);
    // gamma = prox(Wa @ Icol)
    k_wgemm<EP_NONE, 1><<<dim3(NPIX / 64, (PDIM + 63) / 64, BATCH), blk, 0, stream>>>(
        Wa, Icol, Abuf, nullptr, A2, PDIM, NDIM);
    k_prox_mfma<<<gProx, blk, 0, stream>>>(A2, Sbf, Abuf, lmb, gamma);

    for (int k = 0; k < UNFOLD - 1; ++k) {
        if (k % FREQ == 0 && k != 0) {
            // sim refresh: T = std0 * (Ww @ gamma); sim = (1-nus)*sim + nus*softmax(T)
            k_wgemm<EP_SCALEROW, 0><<<dim3(NPIX / 64, (NDIM + 63) / 64, BATCH), blk, 0, stream>>>(
                Ww, gamma, TR, std0, nullptr, NDIM, PDIM);
            k_sq<<<dim3((BATCH * NPIX + 255) / 256), blk, 0, stream>>>(TR, nullptr, sqb);
            k_gram<<<dim3(NPIX / 64, NPIX / 64, BATCH), blk, 0, stream>>>(TR, nullptr, G);
            k_softmax<1><<<dim3(BATCH * NPIX), blk, 0, stream>>>(G, sqb, Sbf, nu);
        }
        // R = Icol - Wd @ gamma
        k_wgemm<EP_SUBFROM, 0><<<dim3(NPIX / 64, (NDIM + 63) / 64, BATCH), blk, 0, stream>>>(
            Wd, gamma, TR, Icol, nullptr, NDIM, PDIM);
        // A = gamma + Wa @ R  (+ bf16 A^2 side-write)
        k_wgemm<EP_ADD, 1><<<dim3(NPIX / 64, (PDIM + 63) / 64, BATCH), blk, 0, stream>>>(
            Wa, TR, Abuf, gamma, A2, PDIM, NDIM);
        // gamma = prox(A)
        k_prox_mfma<<<gProx, blk, 0, stream>>>(A2, Sbf, Abuf, lmb + (size_t)(k + 1) * PDIM, gamma);
    }
    // out_all = Ww @ gamma + mean
    k_wgemm<EP_ADDCOL, 0><<<dim3(NPIX / 64, (NDIM + 63) / 64, BATCH), blk, 0, stream>>>(
        Ww, gamma, TR, meanp, nullptr, NDIM, PDIM);
    // fold back with overlap averaging
    k_col2im<<<dim3((BATCH * NCH * IMGH * IMGH + 255) / 256), blk, 0, stream>>>(TR, out);
}

// Round 3
// 1087.551 us; speedup vs baseline: 3.0898x; 1.3905x over previous
//
#include <hip/hip_runtime.h>
#include <math.h>

#define NPIX 2304      // 48*48 patch positions
#define NDIM 243       // 3*9*9 patch dim
#define PDIM 256       // filters
#define BATCH 2
#define HO 48
#define IMGH 56
#define NCH 3
#define UNFOLD 12
#define FREQ 6

typedef __attribute__((ext_vector_type(8))) short bf16x8;
typedef __attribute__((ext_vector_type(4))) float f32x4;
typedef unsigned short ushort_t;

__device__ inline unsigned short f2bf(float x) {
    union { float f; unsigned u; } v; v.f = x;
    unsigned r = (v.u + 0x7FFFu + ((v.u >> 16) & 1u)) >> 16;
    return (unsigned short)r;
}
__device__ inline float bf2f(unsigned short u) {
    return __uint_as_float(((unsigned)u) << 16);
}

// ---------------- precompute M = Wa@Wd, Q = Ww^T diag(std0^2) Ww (both 256x256, split bf16) ----
__global__ __launch_bounds__(256) void k_precomp(const float* __restrict__ Wa,
                                                 const float* __restrict__ Wd,
                                                 const float* __restrict__ Ww,
                                                 const float* __restrict__ std0,
                                                 ushort_t* __restrict__ Mh, ushort_t* __restrict__ Ml,
                                                 ushort_t* __restrict__ Qh, ushort_t* __restrict__ Ql) {
    int p = blockIdx.x, q = threadIdx.x;
    float m = 0.f, qv = 0.f;
    for (int c = 0; c < NDIM; ++c) {
        float wap = Wa[p * NDIM + c];
        float wdq = Wd[c * PDIM + q];
        m += wap * wdq;
        float s = std0[c];
        qv += s * s * Ww[c * PDIM + p] * Ww[c * PDIM + q];
    }
    int off = p * PDIM + q;
    unsigned short h = f2bf(m);
    Mh[off] = h; Ml[off] = f2bf(m - bf2f(h));
    h = f2bf(qv);
    Qh[off] = h; Ql[off] = f2bf(qv - bf2f(h));
}

// ---------------- im2col + mean subtraction + scaled transposed split-bf16 + sq ----------------
__global__ __launch_bounds__(256) void k_im2col(const float* __restrict__ I,
                                                float* __restrict__ Icol,
                                                float* __restrict__ meanp,
                                                ushort_t* __restrict__ XTh,
                                                ushort_t* __restrict__ XTl,
                                                const float* __restrict__ std0,
                                                float* __restrict__ sqb) {
    int col = blockIdx.x % NPIX;
    int b = blockIdx.x / NPIX;
    int oi = col / HO, oj = col % HO;
    int t = threadIdx.x;
    float v = 0.f;
    if (t < NDIM) {
        int c = t / 81, rem = t % 81, ki = rem / 9, kj = rem % 9;
        v = I[((size_t)(b * NCH + c) * IMGH + (oi + ki)) * IMGH + (oj + kj)];
    }
    __shared__ float red[256];
    red[t] = v;
    __syncthreads();
    for (int s = 128; s > 0; s >>= 1) {
        if (t < s) red[t] += red[t + s];
        __syncthreads();
    }
    float mean = red[0] / (float)NDIM;
    __syncthreads();
    float x = 0.f;
    if (t < NDIM) {
        Icol[((size_t)b * NDIM + t) * NPIX + col] = v - mean;
        x = (v - mean) * std0[t];
    }
    red[t] = x * x;
    __syncthreads();
    for (int s = 128; s > 0; s >>= 1) {
        if (t < s) red[t] += red[t + s];
        __syncthreads();
    }
    if (t == 0) { meanp[b * NPIX + col] = mean; sqb[b * NPIX + col] = red[0]; }
    unsigned short h = f2bf(x);
    size_t xoff = ((size_t)b * NPIX + col) * 256 + t;
    XTh[xoff] = h;
    XTl[xoff] = f2bf(x - bf2f(h));
}

// ---------------- NT split-bf16 MFMA GEMM, K=256 ----------------
// D[m][n] = sum_k A[m][k]*B[n][k], A = Ah+Al, B = Bh+Bl (3-product split)
// EPI 0: C[gm*ldC+gn] = acc (fp32)
// EPI 1: Coh/Col[gm*256+gn] = split(acc)
// EPI 2: v = E1 + E2 - acc; C = v; C2 = bf16(v*v)
template<int TM, int EPI>
__global__ __launch_bounds__(256) void k_ntgemm(const ushort_t* __restrict__ Ah,
                                                const ushort_t* __restrict__ Al,
                                                const ushort_t* __restrict__ Bh,
                                                const ushort_t* __restrict__ Bl,
                                                size_t sA, size_t sB, size_t sC,
                                                float* __restrict__ C,
                                                ushort_t* __restrict__ C2,
                                                ushort_t* __restrict__ Coh,
                                                ushort_t* __restrict__ Col,
                                                const float* __restrict__ E1,
                                                const float* __restrict__ E2,
                                                int ldC) {
    int b = blockIdx.z;
    int n0 = blockIdx.x * 64;
    int m0 = blockIdx.y * TM;
    int tid = threadIdx.x;
    int w = tid >> 6, l = tid & 63, lm = l & 15, kh = l >> 4;
    int wm = (TM == 64) ? w * 16 : (w & 1) * 16;
    int wn = (TM == 64) ? 0 : (w >> 1) * 32;
    const int NF = (TM == 64) ? 4 : 2;
    const ushort_t* Aph = Ah + b * sA + (size_t)(m0 + wm + lm) * 256 + kh * 8;
    const ushort_t* Apl = Al + b * sA + (size_t)(m0 + wm + lm) * 256 + kh * 8;
    const ushort_t* Bph = Bh + b * sB + (size_t)(n0 + wn + lm) * 256 + kh * 8;
    const ushort_t* Bpl = Bl + b * sB + (size_t)(n0 + wn + lm) * 256 + kh * 8;
    f32x4 acc[4];
    #pragma unroll
    for (int n = 0; n < 4; ++n) acc[n] = (f32x4){0.f, 0.f, 0.f, 0.f};
    #pragma unroll
    for (int k = 0; k < 256; k += 32) {
        bf16x8 ah = *reinterpret_cast<const bf16x8*>(Aph + k);
        bf16x8 al = *reinterpret_cast<const bf16x8*>(Apl + k);
        #pragma unroll
        for (int n = 0; n < NF; ++n) {
            bf16x8 bh = *reinterpret_cast<const bf16x8*>(Bph + (size_t)n * 16 * 256 + k);
            bf16x8 bl = *reinterpret_cast<const bf16x8*>(Bpl + (size_t)n * 16 * 256 + k);
            acc[n] = __builtin_amdgcn_mfma_f32_16x16x32_bf16(ah, bh, acc[n], 0, 0, 0);
            acc[n] = __builtin_amdgcn_mfma_f32_16x16x32_bf16(ah, bl, acc[n], 0, 0, 0);
            acc[n] = __builtin_amdgcn_mfma_f32_16x16x32_bf16(al, bh, acc[n], 0, 0, 0);
        }
    }
    #pragma unroll
    for (int n = 0; n < NF; ++n) {
        #pragma unroll
        for (int r = 0; r < 4; ++r) {
            int gm = m0 + wm + kh * 4 + r;
            int gn = n0 + wn + n * 16 + lm;
            float v = acc[n][r];
            if (EPI == 0) {
                C[b * sC + (size_t)gm * ldC + gn] = v;
            } else if (EPI == 1) {
                size_t off = b * sC + (size_t)gm * 256 + gn;
                unsigned short h = f2bf(v);
                Coh[off] = h; Col[off] = f2bf(v - bf2f(h));
            } else {
                size_t off = b * sC + (size_t)gm * ldC + gn;
                float o = E1[off] + E2[off] - v;
                C[off] = o;
                C2[off] = f2bf(o * o);
            }
        }
    }
}

// ---------------- fp32 W@X GEMM with fused epilogues (kept for K=243 edges) ----------------
#define EP_NONE 0
#define EP_ADDCOL 3   // C = WX + E[b,n]  (E = mean_patch)

template<int EP, int WSQ>
__global__ __launch_bounds__(256) void k_wgemm(const float* __restrict__ W,
                                               const float* __restrict__ X,
                                               float* __restrict__ C,
                                               const float* __restrict__ E,
                                               ushort_t* __restrict__ Csq,
                                               int M, int K) {
    int b = blockIdx.z;
    int m0 = blockIdx.y * 64;
    int n0 = blockIdx.x * 64;
    const float* Xb = X + (size_t)b * K * NPIX;
    __shared__ float Ws[16][65];
    __shared__ float Xs[16][64];
    int tid = threadIdx.x;
    int tx = tid % 16, ty = tid / 16;
    int wm = tid / 4, wq = (tid % 4) * 4;
    int lk = tid / 16, lq = (tid % 16) * 4;
    float acc[4][4] = {};
    int nk = (K + 15) / 16;
    for (int t = 0; t < nk; ++t) {
        int k0 = t * 16;
        float wv[4];
        int gm = m0 + wm;
        #pragma unroll
        for (int q = 0; q < 4; ++q) {
            int k = k0 + wq + q;
            wv[q] = (gm < M && k < K) ? W[(size_t)gm * K + k] : 0.f;
        }
        float4 xv = make_float4(0.f, 0.f, 0.f, 0.f);
        int gk = k0 + lk;
        if (gk < K) xv = *reinterpret_cast<const float4*>(Xb + (size_t)gk * NPIX + n0 + lq);
        __syncthreads();
        #pragma unroll
        for (int q = 0; q < 4; ++q) Ws[wq + q][wm] = wv[q];
        *reinterpret_cast<float4*>(&Xs[lk][lq]) = xv;
        __syncthreads();
        #pragma unroll
        for (int kk = 0; kk < 16; ++kk) {
            float a[4], bb[4];
            #pragma unroll
            for (int q = 0; q < 4; ++q) { a[q] = Ws[kk][ty*4+q]; bb[q] = Xs[kk][tx*4+q]; }
            #pragma unroll
            for (int q = 0; q < 4; ++q)
                #pragma unroll
                for (int r = 0; r < 4; ++r) acc[q][r] += a[q] * bb[r];
        }
    }
    float* Cb = C + (size_t)b * M * NPIX;
    #pragma unroll
    for (int q = 0; q < 4; ++q) {
        int m = m0 + ty * 4 + q;
        if (m >= M) break;
        size_t off = (size_t)m * NPIX + n0 + tx * 4;
        float o[4];
        #pragma unroll
        for (int r = 0; r < 4; ++r) {
            float v = acc[q][r];
            if (EP == EP_ADDCOL) v = v + E[b * NPIX + n0 + tx * 4 + r];
            o[r] = v;
        }
        *reinterpret_cast<float4*>(Cb + off) = make_float4(o[0], o[1], o[2], o[3]);
        if (WSQ) {
            ushort_t* Qb = Csq + (size_t)b * M * NPIX + off;
            #pragma unroll
            for (int r = 0; r < 4; ++r) Qb[r] = f2bf(o[r] * o[r]);
        }
    }
}

// ---------------- diag extract: sqb[b,i] = G[b,i,i] ----------------
__global__ void k_diag(const float* __restrict__ G, float* __restrict__ sqb) {
    int idx = blockIdx.x * blockDim.x + threadIdx.x;
    if (idx >= BATCH * NPIX) return;
    int b = idx / NPIX, i = idx % NPIX;
    sqb[idx] = G[(size_t)b * NPIX * NPIX + (size_t)i * NPIX + i];
}

// ---------------- row softmax -> bf16 transposed sim, optional blend ----------------
template<int BLEND>
__global__ __launch_bounds__(256) void k_softmax(float* __restrict__ G,
                                                 const float* __restrict__ sq,
                                                 ushort_t* __restrict__ Sbf,
                                                 const float* __restrict__ nu) {
    int b = blockIdx.x / NPIX;
    int j = blockIdx.x % NPIX;
    float* Grow = G + ((size_t)b * NPIX + j) * NPIX;
    const float* sqb = sq + b * NPIX;
    int t = threadIdx.x;
    __shared__ float red[256];
    float m = -1e30f;
    for (int i = t; i < NPIX; i += 256) {
        float v = 2.f * Grow[i] - sqb[i];
        m = fmaxf(m, v);
    }
    red[t] = m; __syncthreads();
    for (int s = 128; s > 0; s >>= 1) { if (t < s) red[t] = fmaxf(red[t], red[t+s]); __syncthreads(); }
    m = red[0];
    __syncthreads();
    float ssum = 0.f;
    for (int i = t; i < NPIX; i += 256) {
        float e = expf(2.f * Grow[i] - sqb[i] - m);
        Grow[i] = e;
        ssum += e;
    }
    red[t] = ssum; __syncthreads();
    for (int s = 128; s > 0; s >>= 1) { if (t < s) red[t] += red[t+s]; __syncthreads(); }
    float inv = 1.f / red[0];
    ushort_t* Srow = Sbf + ((size_t)b * NPIX + j) * NPIX;
    if (BLEND) {
        float nus = 1.f / (1.f + expf(-nu[0]));
        for (int i = t; i < NPIX; i += 256)
            Srow[i] = f2bf((1.f - nus) * bf2f(Srow[i]) + nus * (Grow[i] * inv));
    } else {
        for (int i = t; i < NPIX; i += 256)
            Srow[i] = f2bf(Grow[i] * inv);
    }
}

// ---------------- MFMA group prox, ptile=32, emits gamma fp32 + gammaT split bf16 ----------------
__global__ __launch_bounds__(256) void k_prox_mfma(const ushort_t* __restrict__ A2,
                                                   const ushort_t* __restrict__ Sbf,
                                                   const float* __restrict__ A,
                                                   const float* __restrict__ theta,
                                                   float* __restrict__ Out,
                                                   ushort_t* __restrict__ gTh,
                                                   ushort_t* __restrict__ gTl) {
    int b = blockIdx.z;
    int p0 = blockIdx.y * 32;
    int j0 = blockIdx.x * 64;
    int tid = threadIdx.x;
    int w = tid >> 6, l = tid & 63, lm = l & 15, kh = l >> 4;
    const ushort_t* Ap0 = A2 + ((size_t)b * PDIM + p0 + lm) * NPIX + kh * 8;
    const ushort_t* Ap1 = Ap0 + (size_t)16 * NPIX;
    const ushort_t* Sp  = Sbf + ((size_t)b * NPIX + j0 + lm) * NPIX + kh * 8;
    f32x4 acc[2][4];
    #pragma unroll
    for (int mi = 0; mi < 2; ++mi)
        #pragma unroll
        for (int n = 0; n < 4; ++n) acc[mi][n] = (f32x4){0.f, 0.f, 0.f, 0.f};
    int kbeg = w * (NPIX / 4);
    for (int k = kbeg; k < kbeg + NPIX / 4; k += 32) {
        bf16x8 a0 = *reinterpret_cast<const bf16x8*>(Ap0 + k);
        bf16x8 a1 = *reinterpret_cast<const bf16x8*>(Ap1 + k);
        #pragma unroll
        for (int n = 0; n < 4; ++n) {
            bf16x8 bv = *reinterpret_cast<const bf16x8*>(Sp + (size_t)n * 16 * NPIX + k);
            acc[0][n] = __builtin_amdgcn_mfma_f32_16x16x32_bf16(a0, bv, acc[0][n], 0, 0, 0);
            acc[1][n] = __builtin_amdgcn_mfma_f32_16x16x32_bf16(a1, bv, acc[1][n], 0, 0, 0);
        }
    }
    __shared__ float red[4][32][65];
    #pragma unroll
    for (int mi = 0; mi < 2; ++mi)
        #pragma unroll
        for (int n = 0; n < 4; ++n)
            #pragma unroll
            for (int r = 0; r < 4; ++r)
                red[w][mi * 16 + kh * 4 + r][n * 16 + lm] = acc[mi][n][r];
    __syncthreads();
    float vout[8];
    #pragma unroll
    for (int it = 0; it < 8; ++it) {
        int linear = tid + it * 256;
        int m = linear >> 6, n = linear & 63;
        float s = red[0][m][n] + red[1][m][n] + red[2][m][n] + red[3][m][n];
        float n2 = sqrtf(s + 1e-8f);
        float th = theta[p0 + m];
        size_t off = ((size_t)b * PDIM + p0 + m) * NPIX + j0 + n;
        float v = fmaxf(1.f - th / n2, 0.f) * A[off];
        Out[off] = v;
        vout[it] = v;
    }
    __syncthreads();
    // transpose staging (alias red): tb[n(64)][m(32)] stride 33, hi/lo
    ushort_t* tb_h = (ushort_t*)&red[0][0][0];
    ushort_t* tb_l = tb_h + 64 * 33;
    #pragma unroll
    for (int it = 0; it < 8; ++it) {
        int linear = tid + it * 256;
        int m = linear >> 6, n = linear & 63;
        unsigned short h = f2bf(vout[it]);
        tb_h[n * 33 + m] = h;
        tb_l[n * 33 + m] = f2bf(vout[it] - bf2f(h));
    }
    __syncthreads();
    int jj = tid >> 2, seg = (tid & 3) * 8;
    size_t go = ((size_t)b * NPIX + j0 + jj) * PDIM + p0 + seg;
    ushort_t th8[8], tl8[8];
    #pragma unroll
    for (int e = 0; e < 8; ++e) { th8[e] = tb_h[jj * 33 + seg + e]; tl8[e] = tb_l[jj * 33 + seg + e]; }
    *reinterpret_cast<bf16x8*>(gTh + go) = *reinterpret_cast<const bf16x8*>(th8);
    *reinterpret_cast<bf16x8*>(gTl + go) = *reinterpret_cast<const bf16x8*>(tl8);
}

// ---------------- col2im with overlap averaging ----------------
__global__ void k_col2im(const float* __restrict__ T, float* __restrict__ out) {
    int idx = blockIdx.x * blockDim.x + threadIdx.x;
    int total = BATCH * NCH * IMGH * IMGH;
    if (idx >= total) return;
    int x = idx % IMGH; int tmp = idx / IMGH;
    int y = tmp % IMGH; tmp /= IMGH;
    int c = tmp % NCH; int b = tmp / NCH;
    int kiLo = max(0, y - (HO - 1)), kiHi = min(8, y);
    int kjLo = max(0, x - (HO - 1)), kjHi = min(8, x);
    float s = 0.f;
    for (int ki = kiLo; ki <= kiHi; ++ki)
        for (int kj = kjLo; kj <= kjHi; ++kj) {
            int ch = c * 81 + ki * 9 + kj;
            s += T[((size_t)b * NDIM + ch) * NPIX + (y - ki) * HO + (x - kj)];
        }
    int cnt = (kiHi - kiLo + 1) * (kjHi - kjLo + 1);
    out[idx] = s / (float)cnt;
}

extern "C" void kernel_launch(void* const* d_in, const int* in_sizes, int n_in,
                              void* d_out, int out_size, void* d_ws, size_t ws_size,
                              hipStream_t stream) {
    const float* I    = (const float*)d_in[0];
    const float* Wa   = (const float*)d_in[1];  // (256,243)
    const float* Wd   = (const float*)d_in[2];  // (243,256)
    const float* Ww   = (const float*)d_in[3];  // (243,256)
    const float* std0 = (const float*)d_in[4];  // (243)
    const float* lmb  = (const float*)d_in[5];  // (12,256)
    const float* nu   = (const float*)d_in[6];  // (1)
    float* out = (float*)d_out;
    float* ws = (float*)d_ws;

    const size_t NP256 = (size_t)NPIX * 256;
    size_t off = 0;
    auto alloc = [&](size_t n) { float* p = ws + off; off += (n + 63) & ~(size_t)63; return p; };
    float* Icol  = alloc((size_t)BATCH * NDIM * NPIX);
    float* TR    = alloc((size_t)BATCH * NDIM * NPIX);
    float* WaI   = alloc((size_t)BATCH * PDIM * NPIX);
    float* Abuf  = alloc((size_t)BATCH * PDIM * NPIX);
    float* gamma = alloc((size_t)BATCH * PDIM * NPIX);
    float* G     = alloc((size_t)BATCH * NPIX * NPIX);
    ushort_t* Sbf = (ushort_t*)alloc((size_t)BATCH * NPIX * NPIX / 2);
    ushort_t* A2  = (ushort_t*)alloc((size_t)BATCH * PDIM * NPIX / 2);
    ushort_t* XTh = (ushort_t*)alloc(BATCH * NP256 / 2);
    ushort_t* XTl = (ushort_t*)alloc(BATCH * NP256 / 2);
    ushort_t* gTh = (ushort_t*)alloc(BATCH * NP256 / 2);
    ushort_t* gTl = (ushort_t*)alloc(BATCH * NP256 / 2);
    ushort_t* HTh = (ushort_t*)alloc(BATCH * NP256 / 2);
    ushort_t* HTl = (ushort_t*)alloc(BATCH * NP256 / 2);
    ushort_t* Mh  = (ushort_t*)alloc(PDIM * PDIM / 2);
    ushort_t* Ml  = (ushort_t*)alloc(PDIM * PDIM / 2);
    ushort_t* Qh  = (ushort_t*)alloc(PDIM * PDIM / 2);
    ushort_t* Ql  = (ushort_t*)alloc(PDIM * PDIM / 2);
    float* meanp = alloc((size_t)BATCH * NPIX);
    float* sqb   = alloc((size_t)BATCH * NPIX);
    (void)ws_size; (void)in_sizes; (void)n_in; (void)out_size;

    dim3 blk(256);
    dim3 gProx(NPIX / 64, PDIM / 32, BATCH);

    k_precomp<<<dim3(PDIM), blk, 0, stream>>>(Wa, Wd, Ww, std0, Mh, Ml, Qh, Ql);
    k_im2col<<<dim3(BATCH * NPIX), blk, 0, stream>>>(I, Icol, meanp, XTh, XTl, std0, sqb);
    // initial gram + softmax
    k_ntgemm<64, 0><<<dim3(NPIX / 64, NPIX / 64, BATCH), blk, 0, stream>>>(
        XTh, XTl, XTh, XTl, NP256, NP256, (size_t)NPIX * NPIX,
        G, nullptr, nullptr, nullptr, nullptr, nullptr, NPIX);
    k_softmax<0><<<dim3(BATCH * NPIX), blk, 0, stream>>>(G, sqb, Sbf, nu);
    // WaI = Wa @ Icol (+ bf16 square side-write)
    k_wgemm<EP_NONE, 1><<<dim3(NPIX / 64, PDIM / 64, BATCH), blk, 0, stream>>>(
        Wa, Icol, WaI, nullptr, A2, PDIM, NDIM);
    // gamma = prox(WaI)
    k_prox_mfma<<<gProx, blk, 0, stream>>>(A2, Sbf, WaI, lmb, gamma, gTh, gTl);

    for (int k = 0; k < UNFOLD - 1; ++k) {
        if (k % FREQ == 0 && k != 0) {
            // HT[j][p] = sum_p' gammaT[j][p'] Q[p'][p]  (Q symmetric)
            k_ntgemm<64, 1><<<dim3(PDIM / 64, NPIX / 64, BATCH), blk, 0, stream>>>(
                gTh, gTl, Qh, Ql, NP256, 0, NP256,
                nullptr, nullptr, HTh, HTl, nullptr, nullptr, 256);
            // G[i][j] = sum_p gammaT[i][p] HT[j][p]
            k_ntgemm<64, 0><<<dim3(NPIX / 64, NPIX / 64, BATCH), blk, 0, stream>>>(
                gTh, gTl, HTh, HTl, NP256, NP256, (size_t)NPIX * NPIX,
                G, nullptr, nullptr, nullptr, nullptr, nullptr, NPIX);
            k_diag<<<dim3((BATCH * NPIX + 255) / 256), blk, 0, stream>>>(G, sqb);
            k_softmax<1><<<dim3(BATCH * NPIX), blk, 0, stream>>>(G, sqb, Sbf, nu);
        }
        // A = WaI + gamma - M@gamma   (M symmetric, B-op = gammaT)
        k_ntgemm<32, 2><<<dim3(NPIX / 64, PDIM / 32, BATCH), blk, 0, stream>>>(
            Mh, Ml, gTh, gTl, 0, NP256, (size_t)PDIM * NPIX,
            Abuf, A2, nullptr, nullptr, WaI, gamma, NPIX);
        // gamma = prox(A)
        k_prox_mfma<<<gProx, blk, 0, stream>>>(
            A2, Sbf, Abuf, lmb + (size_t)(k + 1) * PDIM, gamma, gTh, gTl);
    }
    // out_all = Ww @ gamma + mean
    k_wgemm<EP_ADDCOL, 0><<<dim3(NPIX / 64, (NDIM + 63) / 64, BATCH), blk, 0, stream>>>(
        Ww, gamma, TR, meanp, nullptr, NDIM, PDIM);
    k_col2im<<<dim3((BATCH * NCH * IMGH * IMGH + 255) / 256), blk, 0, stream>>>(TR, out);
}

// Round 4
// 631.948 us; speedup vs baseline: 5.3174x; 1.7210x over previous
//
#include <hip/hip_runtime.h>
#include <math.h>

#define NPIX 2304      // 48*48 patch positions
#define NDIM 243       // 3*9*9 patch dim
#define PDIM 256       // filters
#define BATCH 2
#define HO 48
#define IMGH 56
#define NCH 3
#define UNFOLD 12
#define FREQ 6

typedef __attribute__((ext_vector_type(8))) short bf16x8;
typedef __attribute__((ext_vector_type(4))) float f32x4;
typedef unsigned short ushort_t;

__device__ inline unsigned short f2bf(float x) {
    union { float f; unsigned u; } v; v.f = x;
    unsigned r = (v.u + 0x7FFFu + ((v.u >> 16) & 1u)) >> 16;
    return (unsigned short)r;
}
__device__ inline float bf2f(unsigned short u) {
    return __uint_as_float(((unsigned)u) << 16);
}

// async 16B/lane global->LDS; lds dest = uniform base + lane*16 (linear)
__device__ __forceinline__ void gload16(const ushort_t* g, ushort_t* s) {
    __builtin_amdgcn_global_load_lds(
        (__attribute__((address_space(1))) void*)g,
        (__attribute__((address_space(3))) void*)s, 16, 0, 0);
}

// ---------------- precompute: M=Wa@Wd, Q=Ww^T diag(std0^2) Ww, Wa/Ww split-bf16 (K-pad 256) ----
__global__ __launch_bounds__(256) void k_precomp(const float* __restrict__ Wa,
                                                 const float* __restrict__ Wd,
                                                 const float* __restrict__ Ww,
                                                 const float* __restrict__ std0,
                                                 ushort_t* __restrict__ Mh, ushort_t* __restrict__ Ml,
                                                 ushort_t* __restrict__ Qh, ushort_t* __restrict__ Ql,
                                                 ushort_t* __restrict__ Wah, ushort_t* __restrict__ Wal,
                                                 ushort_t* __restrict__ Wwh, ushort_t* __restrict__ Wwl) {
    int p = blockIdx.x, q = threadIdx.x;
    float m = 0.f, qv = 0.f;
    for (int c = 0; c < NDIM; ++c) {
        m += Wa[p * NDIM + c] * Wd[c * PDIM + q];
        float s = std0[c];
        qv += s * s * Ww[c * PDIM + p] * Ww[c * PDIM + q];
    }
    int off = p * PDIM + q;
    unsigned short h = f2bf(m);
    Mh[off] = h; Ml[off] = f2bf(m - bf2f(h));
    h = f2bf(qv);
    Qh[off] = h; Ql[off] = f2bf(qv - bf2f(h));
    float wa = (q < NDIM) ? Wa[p * NDIM + q] : 0.f;
    h = f2bf(wa);
    Wah[off] = h; Wal[off] = f2bf(wa - bf2f(h));
    float ww = (p < NDIM) ? Ww[p * PDIM + q] : 0.f;
    h = f2bf(ww);
    Wwh[off] = h; Wwl[off] = f2bf(ww - bf2f(h));
}

// ---------------- im2col: mean-sub, emit scaled + unscaled transposed split-bf16 (K-pad 256) ----
__global__ __launch_bounds__(256) void k_im2col(const float* __restrict__ I,
                                                float* __restrict__ meanp,
                                                ushort_t* __restrict__ XTsh, ushort_t* __restrict__ XTsl,
                                                ushort_t* __restrict__ XTuh, ushort_t* __restrict__ XTul,
                                                const float* __restrict__ std0) {
    int col = blockIdx.x % NPIX;
    int b = blockIdx.x / NPIX;
    int oi = col / HO, oj = col % HO;
    int t = threadIdx.x;
    float v = 0.f;
    if (t < NDIM) {
        int c = t / 81, rem = t % 81, ki = rem / 9, kj = rem % 9;
        v = I[((size_t)(b * NCH + c) * IMGH + (oi + ki)) * IMGH + (oj + kj)];
    }
    __shared__ float red[256];
    red[t] = v;
    __syncthreads();
    for (int s = 128; s > 0; s >>= 1) {
        if (t < s) red[t] += red[t + s];
        __syncthreads();
    }
    float mean = red[0] / (float)NDIM;
    float xu = (t < NDIM) ? v - mean : 0.f;
    float xs = (t < NDIM) ? xu * std0[t] : 0.f;
    if (t == 0) meanp[b * NPIX + col] = mean;
    size_t xo = ((size_t)b * NPIX + col) * 256 + t;
    unsigned short h = f2bf(xu);
    XTuh[xo] = h; XTul[xo] = f2bf(xu - bf2f(h));
    h = f2bf(xs);
    XTsh[xo] = h; XTsl[xo] = f2bf(xs - bf2f(h));
}

// ---------------- unified LDS-staged NT split-bf16 MFMA GEMM ----------------
// D[m][n] = sum_k A[m][k]*B[n][k]; A=Ah(+Al), B=Bh(+Bl); 2-phase double-buffered
// global_load_lds staging with XOR-swizzled source addresses.
#define EPI_G 0        // C[m*ldC+n]=acc fp32; diag -> sqd
#define EPI_SPLITOUT 1 // Oh/Ol[m*ldC+n] = split(acc)
#define EPI_ITER 2     // o=E1+E2-acc; C=o; C2=bf16(o*o)
#define EPI_WAI 3      // C=acc; C2=bf16(acc*acc)
#define EPI_ADDCOL 4   // C=acc+E1[b,n]
#define EPI_PROX 5     // shrink + POut fp32 + transposed split gT

template<int TM, int TN, int SPLIT, int EPI>
__global__ __launch_bounds__(256) void k_sgemm(
    const ushort_t* __restrict__ Ah, const ushort_t* __restrict__ Al,
    const ushort_t* __restrict__ Bh, const ushort_t* __restrict__ Bl,
    int ldA, int ldB, size_t sA, size_t sB, int K,
    float* __restrict__ C, ushort_t* __restrict__ C2,
    ushort_t* __restrict__ Oh, ushort_t* __restrict__ Ol,
    const float* __restrict__ E1, const float* __restrict__ E2,
    int ldC, size_t sC,
    const float* __restrict__ EA, const float* __restrict__ theta,
    float* __restrict__ sqd,
    float* __restrict__ POut, ushort_t* __restrict__ gTh, ushort_t* __restrict__ gTl) {

    constexpr int CA = TM / 16, CB = TN / 16;
    constexpr int CHUNKS = (1 + SPLIT) * (CA + CB);
    constexpr int CPW = CHUNKS / 4;
    constexpr int BUFE = CHUNKS * 512;          // elems per buffer
    constexpr int TRE = (EPI == EPI_PROX) ? 2 * 64 * 66 : 0;
    constexpr int LDSE = (2 * BUFE > TRE) ? 2 * BUFE : TRE;
    constexpr int WM = TM / 2, WN = TN / 2;
    constexpr int MF = WM / 16, NF = WN / 16;

    __shared__ ushort_t lds[LDSE];

    int b = blockIdx.z;
    int n0 = blockIdx.x * TN;
    int m0 = blockIdx.y * TM;
    int tid = threadIdx.x;
    int w = tid >> 6, l = tid & 63, lm = l & 15, kh = l >> 4;
    int wm = (w >> 1) * WM, wn = (w & 1) * WN;

    const ushort_t* pAh = Ah + b * sA;
    const ushort_t* pAl = SPLIT ? Al + b * sA : nullptr;
    const ushort_t* pBh = Bh + b * sB;
    const ushort_t* pBl = SPLIT ? Bl + b * sB : nullptr;

    // staging: lane's linear-LDS slot (l&3) holds global k-slot (l&3)^((l>>3)&3)
    int srow = l >> 2;
    int sslot = ((l & 3) ^ ((l >> 3) & 3)) << 3;

    auto stage = [&](int bsel, int k0) {
        ushort_t* bb = lds + bsel * BUFE;
        #pragma unroll
        for (int i = 0; i < CPW; ++i) {
            int c = w * CPW + i;
            const ushort_t* src; int ld; int rowg;
            if (SPLIT) {
                if (c < CA)               { src = pAh; ld = ldA; rowg = m0 + c * 16; }
                else if (c < 2 * CA)      { src = pAl; ld = ldA; rowg = m0 + (c - CA) * 16; }
                else if (c < 2 * CA + CB) { src = pBh; ld = ldB; rowg = n0 + (c - 2 * CA) * 16; }
                else                      { src = pBl; ld = ldB; rowg = n0 + (c - 2 * CA - CB) * 16; }
            } else {
                if (c < CA) { src = pAh; ld = ldA; rowg = m0 + c * 16; }
                else        { src = pBh; ld = ldB; rowg = n0 + (c - CA) * 16; }
            }
            const ushort_t* g = src + (size_t)(rowg + srow) * ld + k0 + sslot;
            gload16(g, bb + (size_t)c * 512);
        }
    };

    f32x4 acc[MF][NF];
    #pragma unroll
    for (int mf = 0; mf < MF; ++mf)
        #pragma unroll
        for (int nf = 0; nf < NF; ++nf) acc[mf][nf] = (f32x4){0.f, 0.f, 0.f, 0.f};

    int sw = ((kh ^ ((lm >> 1) & 3)) << 3);   // read-side swizzled slot (elems)
    const int NT = K / 32;

    stage(0, 0);
    __syncthreads();
    for (int t = 0; t < NT; ++t) {
        if (t + 1 < NT) stage((t + 1) & 1, (t + 1) * 32);
        ushort_t* bb = lds + (t & 1) * BUFE;
        ushort_t* LA_h = bb;
        ushort_t* LA_l = bb + CA * 512;
        ushort_t* LB_h = bb + (1 + SPLIT) * CA * 512;
        ushort_t* LB_l = LB_h + CB * 512;
        bf16x8 afh[MF], afl[MF], bfh[NF], bfl[NF];
        #pragma unroll
        for (int mf = 0; mf < MF; ++mf) {
            int off = (wm + mf * 16 + lm) * 32 + sw;
            afh[mf] = *reinterpret_cast<const bf16x8*>(LA_h + off);
            if (SPLIT) afl[mf] = *reinterpret_cast<const bf16x8*>(LA_l + off);
        }
        #pragma unroll
        for (int nf = 0; nf < NF; ++nf) {
            int off = (wn + nf * 16 + lm) * 32 + sw;
            bfh[nf] = *reinterpret_cast<const bf16x8*>(LB_h + off);
            if (SPLIT) bfl[nf] = *reinterpret_cast<const bf16x8*>(LB_l + off);
        }
        #pragma unroll
        for (int mf = 0; mf < MF; ++mf)
            #pragma unroll
            for (int nf = 0; nf < NF; ++nf) {
                acc[mf][nf] = __builtin_amdgcn_mfma_f32_16x16x32_bf16(afh[mf], bfh[nf], acc[mf][nf], 0, 0, 0);
                if (SPLIT) {
                    acc[mf][nf] = __builtin_amdgcn_mfma_f32_16x16x32_bf16(afh[mf], bfl[nf], acc[mf][nf], 0, 0, 0);
                    acc[mf][nf] = __builtin_amdgcn_mfma_f32_16x16x32_bf16(afl[mf], bfh[nf], acc[mf][nf], 0, 0, 0);
                }
            }
        __syncthreads();
    }

    if (EPI == EPI_PROX) {
        ushort_t* tbh = lds;
        ushort_t* tbl = lds + 64 * 66;
        #pragma unroll
        for (int mf = 0; mf < MF; ++mf)
            #pragma unroll
            for (int nf = 0; nf < NF; ++nf)
                #pragma unroll
                for (int r = 0; r < 4; ++r) {
                    int pl = wm + mf * 16 + kh * 4 + r;
                    int jl = wn + nf * 16 + lm;
                    int gp = m0 + pl;
                    float n2 = sqrtf(acc[mf][nf][r] + 1e-8f);
                    size_t off = b * sC + (size_t)gp * ldC + (n0 + jl);
                    float v = fmaxf(1.f - theta[gp] / n2, 0.f) * EA[off];
                    POut[off] = v;
                    unsigned short h = f2bf(v);
                    tbh[jl * 66 + pl] = h;
                    tbl[jl * 66 + pl] = f2bf(v - bf2f(h));
                }
        __syncthreads();
        #pragma unroll
        for (int it = 0; it < 2; ++it) {
            int idx = tid + it * 256;
            int jj = idx >> 3, seg = (idx & 7) * 8;
            size_t go = ((size_t)b * NPIX + n0 + jj) * PDIM + m0 + seg;
            bf16x8 vh, vl;
            #pragma unroll
            for (int e = 0; e < 8; ++e) {
                vh[e] = (short)tbh[jj * 66 + seg + e];
                vl[e] = (short)tbl[jj * 66 + seg + e];
            }
            *reinterpret_cast<bf16x8*>(gTh + go) = vh;
            *reinterpret_cast<bf16x8*>(gTl + go) = vl;
        }
    } else {
        #pragma unroll
        for (int mf = 0; mf < MF; ++mf)
            #pragma unroll
            for (int nf = 0; nf < NF; ++nf)
                #pragma unroll
                for (int r = 0; r < 4; ++r) {
                    int gm = m0 + wm + mf * 16 + kh * 4 + r;
                    int gn = n0 + wn + nf * 16 + lm;
                    float v = acc[mf][nf][r];
                    size_t off = b * sC + (size_t)gm * ldC + gn;
                    if (EPI == EPI_G) {
                        C[off] = v;
                        if (gm == gn) sqd[b * NPIX + gm] = v;
                    } else if (EPI == EPI_SPLITOUT) {
                        unsigned short h = f2bf(v);
                        Oh[off] = h; Ol[off] = f2bf(v - bf2f(h));
                    } else if (EPI == EPI_ITER) {
                        float o = E1[off] + E2[off] - v;
                        C[off] = o;
                        C2[off] = f2bf(o * o);
                    } else if (EPI == EPI_WAI) {
                        C[off] = v;
                        C2[off] = f2bf(v * v);
                    } else { // EPI_ADDCOL
                        C[off] = v + E1[b * NPIX + gn];
                    }
                }
    }
}

// ---------------- row softmax (register-resident) -> bf16 transposed sim ----------------
template<int BLEND>
__global__ __launch_bounds__(256) void k_softmax(const float* __restrict__ G,
                                                 const float* __restrict__ sq,
                                                 ushort_t* __restrict__ Sbf,
                                                 const float* __restrict__ nu) {
    int b = blockIdx.x / NPIX;
    int j = blockIdx.x % NPIX;
    const float* Grow = G + ((size_t)b * NPIX + j) * NPIX;
    const float* sqb = sq + (size_t)b * NPIX;
    int t = threadIdx.x;
    float v[9];
    float m = -1e30f;
    #pragma unroll
    for (int i = 0; i < 9; ++i) {
        int ix = t + i * 256;
        v[i] = 2.f * Grow[ix] - sqb[ix];
        m = fmaxf(m, v[i]);
    }
    __shared__ float red[256];
    red[t] = m; __syncthreads();
    for (int s = 128; s > 0; s >>= 1) { if (t < s) red[t] = fmaxf(red[t], red[t+s]); __syncthreads(); }
    m = red[0];
    __syncthreads();
    float ss = 0.f;
    #pragma unroll
    for (int i = 0; i < 9; ++i) { v[i] = expf(v[i] - m); ss += v[i]; }
    red[t] = ss; __syncthreads();
    for (int s = 128; s > 0; s >>= 1) { if (t < s) red[t] += red[t+s]; __syncthreads(); }
    float inv = 1.f / red[0];
    ushort_t* Srow = Sbf + ((size_t)b * NPIX + j) * NPIX;
    if (BLEND) {
        float nus = 1.f / (1.f + expf(-nu[0]));
        #pragma unroll
        for (int i = 0; i < 9; ++i) {
            int ix = t + i * 256;
            Srow[ix] = f2bf((1.f - nus) * bf2f(Srow[ix]) + nus * (v[i] * inv));
        }
    } else {
        #pragma unroll
        for (int i = 0; i < 9; ++i) Srow[t + i * 256] = f2bf(v[i] * inv);
    }
}

// ---------------- col2im with overlap averaging ----------------
__global__ void k_col2im(const float* __restrict__ T, float* __restrict__ out) {
    int idx = blockIdx.x * blockDim.x + threadIdx.x;
    int total = BATCH * NCH * IMGH * IMGH;
    if (idx >= total) return;
    int x = idx % IMGH; int tmp = idx / IMGH;
    int y = tmp % IMGH; tmp /= IMGH;
    int c = tmp % NCH; int b = tmp / NCH;
    int kiLo = max(0, y - (HO - 1)), kiHi = min(8, y);
    int kjLo = max(0, x - (HO - 1)), kjHi = min(8, x);
    float s = 0.f;
    for (int ki = kiLo; ki <= kiHi; ++ki)
        for (int kj = kjLo; kj <= kjHi; ++kj) {
            int ch = c * 81 + ki * 9 + kj;
            s += T[((size_t)b * 256 + ch) * NPIX + (y - ki) * HO + (x - kj)];
        }
    int cnt = (kiHi - kiLo + 1) * (kjHi - kjLo + 1);
    out[idx] = s / (float)cnt;
}

extern "C" void kernel_launch(void* const* d_in, const int* in_sizes, int n_in,
                              void* d_out, int out_size, void* d_ws, size_t ws_size,
                              hipStream_t stream) {
    const float* I    = (const float*)d_in[0];
    const float* Wa   = (const float*)d_in[1];  // (256,243)
    const float* Wd   = (const float*)d_in[2];  // (243,256)
    const float* Ww   = (const float*)d_in[3];  // (243,256)
    const float* std0 = (const float*)d_in[4];  // (243)
    const float* lmb  = (const float*)d_in[5];  // (12,256)
    const float* nu   = (const float*)d_in[6];  // (1)
    float* out = (float*)d_out;
    float* ws = (float*)d_ws;

    const size_t NP256 = (size_t)NPIX * 256;
    size_t off = 0;
    auto alloc = [&](size_t n) { float* p = ws + off; off += (n + 63) & ~(size_t)63; return p; };
    auto allocU = [&](size_t n) { return (ushort_t*)alloc((n + 1) / 2); };

    float* WaI   = alloc((size_t)BATCH * PDIM * NPIX);
    float* Abuf  = alloc((size_t)BATCH * PDIM * NPIX);
    float* gamma = alloc((size_t)BATCH * PDIM * NPIX);
    float* TR    = alloc((size_t)BATCH * 256 * NPIX);
    float* G     = alloc((size_t)BATCH * NPIX * NPIX);
    ushort_t* Sbf  = allocU((size_t)BATCH * NPIX * NPIX);
    ushort_t* A2   = allocU((size_t)BATCH * PDIM * NPIX);
    ushort_t* XTsh = allocU(BATCH * NP256);
    ushort_t* XTsl = allocU(BATCH * NP256);
    ushort_t* XTuh = allocU(BATCH * NP256);
    ushort_t* XTul = allocU(BATCH * NP256);
    ushort_t* gTh  = allocU(BATCH * NP256);
    ushort_t* gTl  = allocU(BATCH * NP256);
    ushort_t* HTh  = allocU(BATCH * NP256);
    ushort_t* HTl  = allocU(BATCH * NP256);
    ushort_t* Mh   = allocU(PDIM * PDIM);
    ushort_t* Ml   = allocU(PDIM * PDIM);
    ushort_t* Qh   = allocU(PDIM * PDIM);
    ushort_t* Ql   = allocU(PDIM * PDIM);
    ushort_t* Wah  = allocU(PDIM * PDIM);
    ushort_t* Wal  = allocU(PDIM * PDIM);
    ushort_t* Wwh  = allocU(PDIM * PDIM);
    ushort_t* Wwl  = allocU(PDIM * PDIM);
    float* meanp = alloc((size_t)BATCH * NPIX);
    float* sqd   = alloc((size_t)BATCH * NPIX);
    (void)ws_size; (void)in_sizes; (void)n_in; (void)out_size;

    dim3 blk(256);
    const size_t sPN = (size_t)PDIM * NPIX;
    const size_t sNN = (size_t)NPIX * NPIX;

    k_precomp<<<dim3(PDIM), blk, 0, stream>>>(Wa, Wd, Ww, std0, Mh, Ml, Qh, Ql, Wah, Wal, Wwh, Wwl);
    k_im2col<<<dim3(BATCH * NPIX), blk, 0, stream>>>(I, meanp, XTsh, XTsl, XTuh, XTul, std0);

    // G = XTs @ XTs^T (+ diag -> sqd)
    k_sgemm<128, 128, 1, EPI_G><<<dim3(NPIX/128, NPIX/128, BATCH), blk, 0, stream>>>(
        XTsh, XTsl, XTsh, XTsl, 256, 256, NP256, NP256, 256,
        G, nullptr, nullptr, nullptr, nullptr, nullptr, NPIX, sNN,
        nullptr, nullptr, sqd, nullptr, nullptr, nullptr);
    k_softmax<0><<<dim3(BATCH * NPIX), blk, 0, stream>>>(G, sqd, Sbf, nu);

    // WaI = Wa @ X (+ A2 = bf16(WaI^2))
    k_sgemm<64, 64, 1, EPI_WAI><<<dim3(NPIX/64, PDIM/64, BATCH), blk, 0, stream>>>(
        Wah, Wal, XTuh, XTul, 256, 256, 0, NP256, 256,
        WaI, A2, nullptr, nullptr, nullptr, nullptr, NPIX, sPN,
        nullptr, nullptr, nullptr, nullptr, nullptr, nullptr);
    // gamma = prox(WaI)
    k_sgemm<64, 64, 0, EPI_PROX><<<dim3(NPIX/64, PDIM/64, BATCH), blk, 0, stream>>>(
        A2, nullptr, Sbf, nullptr, NPIX, NPIX, sPN, sNN, NPIX,
        nullptr, nullptr, nullptr, nullptr, nullptr, nullptr, NPIX, sPN,
        WaI, lmb, nullptr, gamma, gTh, gTl);

    for (int k = 0; k < UNFOLD - 1; ++k) {
        if (k % FREQ == 0 && k != 0) {
            // HT[j][p] = sum_p' gT[j][p'] Q[p'][p]
            k_sgemm<64, 64, 1, EPI_SPLITOUT><<<dim3(PDIM/64, NPIX/64, BATCH), blk, 0, stream>>>(
                gTh, gTl, Qh, Ql, 256, 256, NP256, 0, 256,
                nullptr, nullptr, HTh, HTl, nullptr, nullptr, 256, NP256,
                nullptr, nullptr, nullptr, nullptr, nullptr, nullptr);
            // G[i][j] = sum_p gT[i][p] HT[j][p] (+ diag -> sqd)
            k_sgemm<128, 128, 1, EPI_G><<<dim3(NPIX/128, NPIX/128, BATCH), blk, 0, stream>>>(
                gTh, gTl, HTh, HTl, 256, 256, NP256, NP256, 256,
                G, nullptr, nullptr, nullptr, nullptr, nullptr, NPIX, sNN,
                nullptr, nullptr, sqd, nullptr, nullptr, nullptr);
            k_softmax<1><<<dim3(BATCH * NPIX), blk, 0, stream>>>(G, sqd, Sbf, nu);
        }
        // A = WaI + gamma - M@gamma ; A2 = bf16(A^2)
        k_sgemm<64, 64, 1, EPI_ITER><<<dim3(NPIX/64, PDIM/64, BATCH), blk, 0, stream>>>(
            Mh, Ml, gTh, gTl, 256, 256, 0, NP256, 256,
            Abuf, A2, nullptr, nullptr, WaI, gamma, NPIX, sPN,
            nullptr, nullptr, nullptr, nullptr, nullptr, nullptr);
        // gamma = prox(A)
        k_sgemm<64, 64, 0, EPI_PROX><<<dim3(NPIX/64, PDIM/64, BATCH), blk, 0, stream>>>(
            A2, nullptr, Sbf, nullptr, NPIX, NPIX, sPN, sNN, NPIX,
            nullptr, nullptr, nullptr, nullptr, nullptr, nullptr, NPIX, sPN,
            Abuf, lmb + (size_t)(k + 1) * PDIM, nullptr, gamma, gTh, gTl);
    }
    // out_all = Ww @ gamma + mean
    k_sgemm<64, 64, 1, EPI_ADDCOL><<<dim3(NPIX/64, 256/64, BATCH), blk, 0, stream>>>(
        Wwh, Wwl, gTh, gTl, 256, 256, 0, NP256, 256,
        TR, nullptr, nullptr, nullptr, meanp, nullptr, NPIX, (size_t)256 * NPIX,
        nullptr, nullptr, nullptr, nullptr, nullptr, nullptr);
    k_col2im<<<dim3((BATCH * NCH * IMGH * IMGH + 255) / 256), blk, 0, stream>>>(TR, out);
}